// Round 1
// baseline (4794.967 us; speedup 1.0000x reference)
//
#include <hip/hip_runtime.h>
#include <hip/hip_bf16.h>

#define NN 100000
#define EE 600000
#define RR 3
#define INF 256
#define HFF 256
#define NH 4
#define DD 64
#define CC 153

// ---------------- fp32 tiled GEMM: C[N,256] = A[N,256] @ B[256,256] ----------
__global__ __launch_bounds__(256) void gemm64(const float* __restrict__ A,
                                              const float* __restrict__ B,
                                              float* __restrict__ C, int Nrows) {
    __shared__ float As[16][68];
    __shared__ float Bs[16][68];
    int tid = threadIdx.x;
    int bm = blockIdx.x * 64;
    int bn = blockIdx.y * 64;
    int tx = tid & 15, ty = tid >> 4;
    float acc[4][4] = {};

    int arow = tid >> 2;          // 0..63
    int ak   = (tid & 3) * 4;     // 0,4,8,12
    int brow = tid >> 4;          // 0..15
    int bcol = (tid & 15) * 4;    // 0..60

    for (int k0 = 0; k0 < 256; k0 += 16) {
        float4 av = make_float4(0.f, 0.f, 0.f, 0.f);
        int grow = bm + arow;
        if (grow < Nrows)
            av = *reinterpret_cast<const float4*>(A + (size_t)grow * 256 + k0 + ak);
        As[ak + 0][arow] = av.x; As[ak + 1][arow] = av.y;
        As[ak + 2][arow] = av.z; As[ak + 3][arow] = av.w;
        float4 bv = *reinterpret_cast<const float4*>(B + (size_t)(k0 + brow) * 256 + bn + bcol);
        *reinterpret_cast<float4*>(&Bs[brow][bcol]) = bv;
        __syncthreads();
#pragma unroll
        for (int k = 0; k < 16; ++k) {
            float4 a = *reinterpret_cast<const float4*>(&As[k][ty * 4]);
            float4 b = *reinterpret_cast<const float4*>(&Bs[k][tx * 4]);
            acc[0][0] += a.x * b.x; acc[0][1] += a.x * b.y; acc[0][2] += a.x * b.z; acc[0][3] += a.x * b.w;
            acc[1][0] += a.y * b.x; acc[1][1] += a.y * b.y; acc[1][2] += a.y * b.z; acc[1][3] += a.y * b.w;
            acc[2][0] += a.z * b.x; acc[2][1] += a.z * b.y; acc[2][2] += a.z * b.z; acc[2][3] += a.z * b.w;
            acc[3][0] += a.w * b.x; acc[3][1] += a.w * b.y; acc[3][2] += a.w * b.z; acc[3][3] += a.w * b.w;
        }
        __syncthreads();
    }
#pragma unroll
    for (int i = 0; i < 4; ++i) {
        int row = bm + ty * 4 + i;
        if (row < Nrows) {
            float4 v = make_float4(acc[i][0], acc[i][1], acc[i][2], acc[i][3]);
            *reinterpret_cast<float4*>(C + (size_t)row * 256 + bn + tx * 4) = v;
        }
    }
}

// ------------- per-node attention logits: el/er [N,H] ------------------------
__global__ __launch_bounds__(256) void el_er_kernel(const float* __restrict__ feat,
                                                    const float* __restrict__ al,
                                                    const float* __restrict__ ar,
                                                    float* __restrict__ el,
                                                    float* __restrict__ er) {
    int n = blockIdx.x;
    int tid = threadIdx.x;            // h = tid>>6, d = tid&63
    float v = feat[(size_t)n * 256 + tid];
    float l = v * al[tid];
    float r = v * ar[tid];
    for (int off = 32; off; off >>= 1) {
        l += __shfl_down(l, off);
        r += __shfl_down(r, off);
    }
    if ((tid & 63) == 0) {
        int h = tid >> 6;
        el[n * 4 + h] = l;
        er[n * 4 + h] = r;
    }
}

// ------------- softmax denominator z[N,H] (no max-shift; e is bounded) -------
__global__ __launch_bounds__(256) void edge_z(const int* __restrict__ src,
                                              const int* __restrict__ dst,
                                              const float* __restrict__ el,
                                              const float* __restrict__ er,
                                              float* __restrict__ z, int Ecnt) {
    int idx = blockIdx.x * 256 + threadIdx.x;
    if (idx >= Ecnt * 4) return;
    int e = idx >> 2, h = idx & 3;
    int s = src[e], d = dst[e];
    float v = el[s * 4 + h] + er[d * 4 + h];
    v = v > 0.f ? v : 0.2f * v;
    atomicAdd(&z[d * 4 + h], __expf(v));
}

// ------------- message scatter: acc[dst] += alpha * feat[src] ----------------
__global__ __launch_bounds__(256) void edge_scatter(const int* __restrict__ src,
                                                    const int* __restrict__ dst,
                                                    const float* __restrict__ el,
                                                    const float* __restrict__ er,
                                                    const float* __restrict__ z,
                                                    const float* __restrict__ feat,
                                                    float* __restrict__ acc, int Ecnt) {
    int wid = (blockIdx.x * 256 + threadIdx.x) >> 6;
    int lane = threadIdx.x & 63;
    if (wid >= Ecnt) return;
    int s = src[wid], d = dst[wid];
    const float* fs = feat + (size_t)s * 256;
    float* ad = acc + (size_t)d * 256;
#pragma unroll
    for (int h = 0; h < 4; ++h) {
        float v = el[s * 4 + h] + er[d * 4 + h];
        v = v > 0.f ? v : 0.2f * v;
        float alpha = __expf(v) / z[d * 4 + h];
        atomicAdd(&ad[h * 64 + lane], fs[h * 64 + lane] * alpha);
    }
}

// ------------- acc init with summed per-relation bias ------------------------
__global__ __launch_bounds__(256) void bias_init(float* __restrict__ acc,
                                                 const float* __restrict__ b) {
    size_t idx = (size_t)blockIdx.x * 256 + threadIdx.x;
    if (idx >= (size_t)NN * 256) return;
    int f = idx & 255;
    acc[idx] = b[f] + b[256 + f] + b[512 + f];
}

__global__ __launch_bounds__(256) void relu_kernel(const float* __restrict__ in,
                                                   float* __restrict__ outp) {
    size_t idx = (size_t)blockIdx.x * 256 + threadIdx.x;
    if (idx >= (size_t)NN * 256) return;
    float v = in[idx];
    outp[idx] = v > 0.f ? v : 0.f;
}

// ------------- output linear: out[N,153] = H[N,256] @ Wout[256,153] + bout ---
__global__ __launch_bounds__(256) void out_gemm(const float* __restrict__ Hf,
                                                const float* __restrict__ Wout,
                                                const float* __restrict__ bout,
                                                float* __restrict__ outp, int Nrows) {
    __shared__ float sh[8][256];
    int n0 = blockIdx.x * 8;
    int tid = threadIdx.x;
#pragma unroll
    for (int i = 0; i < 8; ++i) {
        int n = n0 + i;
        sh[i][tid] = (n < Nrows) ? Hf[(size_t)n * 256 + tid] : 0.f;
    }
    __syncthreads();
    if (tid < CC) {
        float s[8] = {};
        for (int k = 0; k < 256; ++k) {
            float w = Wout[k * CC + tid];
#pragma unroll
            for (int i = 0; i < 8; ++i) s[i] += sh[i][k] * w;
        }
        float bb = bout[tid];
#pragma unroll
        for (int i = 0; i < 8; ++i) {
            int n = n0 + i;
            if (n < Nrows) outp[(size_t)n * CC + tid] = s[i] + bb;
        }
    }
}

extern "C" void kernel_launch(void* const* d_in, const int* in_sizes, int n_in,
                              void* d_out, int out_size, void* d_ws, size_t ws_size,
                              hipStream_t stream) {
    const float* x    = (const float*)d_in[0];
    const int*   src  = (const int*)d_in[1];
    const int*   dst  = (const int*)d_in[2];
    const float* W1   = (const float*)d_in[3];
    const float* al1  = (const float*)d_in[4];
    const float* ar1  = (const float*)d_in[5];
    const float* b1   = (const float*)d_in[6];
    const float* W2   = (const float*)d_in[7];
    const float* al2  = (const float*)d_in[8];
    const float* ar2  = (const float*)d_in[9];
    const float* b2   = (const float*)d_in[10];
    const float* Wout = (const float*)d_in[11];
    const float* bout = (const float*)d_in[12];
    float* out = (float*)d_out;

    // workspace layout (floats): feat | h1 | acc | el | er | z   (~312 MB)
    float* ws = (float*)d_ws;
    size_t NF = (size_t)NN * HFF;
    float* feat = ws;
    float* h1   = ws + NF;
    float* acc  = ws + 2 * NF;
    float* el   = ws + 3 * NF;
    float* er   = el + (size_t)NN * NH;
    float* z    = er + (size_t)NN * NH;

    dim3 ggrid((NN + 63) / 64, HFF / 64);
    int nfBlocks = (int)((NF + 255) / 256);

    for (int layer = 0; layer < 2; ++layer) {
        const float* X  = layer ? h1 : x;
        const float* W  = layer ? W2 : W1;
        const float* al = layer ? al2 : al1;
        const float* ar = layer ? ar2 : ar1;
        const float* b  = layer ? b2 : b1;

        bias_init<<<nfBlocks, 256, 0, stream>>>(acc, b);
        for (int r = 0; r < RR; ++r) {
            gemm64<<<ggrid, 256, 0, stream>>>(X, W + (size_t)r * INF * HFF, feat, NN);
            el_er_kernel<<<NN, 256, 0, stream>>>(feat, al + r * NH * DD, ar + r * NH * DD, el, er);
            hipMemsetAsync(z, 0, (size_t)NN * NH * sizeof(float), stream);
            edge_z<<<(EE * 4 + 255) / 256, 256, 0, stream>>>(src + (size_t)r * EE, dst + (size_t)r * EE,
                                                             el, er, z, EE);
            edge_scatter<<<(EE + 3) / 4, 256, 0, stream>>>(src + (size_t)r * EE, dst + (size_t)r * EE,
                                                           el, er, z, feat, acc, EE);
        }
        if (layer == 0)
            relu_kernel<<<nfBlocks, 256, 0, stream>>>(acc, h1);
    }
    out_gemm<<<(NN + 7) / 8, 256, 0, stream>>>(acc, Wout, bout, out, NN);
}

// Round 2
// 2617.809 us; speedup vs baseline: 1.8317x; 1.8317x over previous
//
#include <hip/hip_runtime.h>
#include <hip/hip_bf16.h>

#define NN 100000
#define EE 600000
#define RR 3
#define INF 256
#define HFF 256
#define NH 4
#define DD 64
#define CC 153
#define NB 98   // ceil(NN/1024)

// ---------------- fp32 tiled GEMM: C[N,256] = A[N,256] @ B[256,256] ----------
__global__ __launch_bounds__(256) void gemm64(const float* __restrict__ A,
                                              const float* __restrict__ B,
                                              float* __restrict__ C, int Nrows) {
    __shared__ float As[16][68];
    __shared__ float Bs[16][68];
    int tid = threadIdx.x;
    int bm = blockIdx.x * 64;
    int bn = blockIdx.y * 64;
    int tx = tid & 15, ty = tid >> 4;
    float acc[4][4] = {};

    int arow = tid >> 2;          // 0..63
    int ak   = (tid & 3) * 4;     // 0,4,8,12
    int brow = tid >> 4;          // 0..15
    int bcol = (tid & 15) * 4;    // 0..60

    for (int k0 = 0; k0 < 256; k0 += 16) {
        float4 av = make_float4(0.f, 0.f, 0.f, 0.f);
        int grow = bm + arow;
        if (grow < Nrows)
            av = *reinterpret_cast<const float4*>(A + (size_t)grow * 256 + k0 + ak);
        As[ak + 0][arow] = av.x; As[ak + 1][arow] = av.y;
        As[ak + 2][arow] = av.z; As[ak + 3][arow] = av.w;
        float4 bv = *reinterpret_cast<const float4*>(B + (size_t)(k0 + brow) * 256 + bn + bcol);
        *reinterpret_cast<float4*>(&Bs[brow][bcol]) = bv;
        __syncthreads();
#pragma unroll
        for (int k = 0; k < 16; ++k) {
            float4 a = *reinterpret_cast<const float4*>(&As[k][ty * 4]);
            float4 b = *reinterpret_cast<const float4*>(&Bs[k][tx * 4]);
            acc[0][0] += a.x * b.x; acc[0][1] += a.x * b.y; acc[0][2] += a.x * b.z; acc[0][3] += a.x * b.w;
            acc[1][0] += a.y * b.x; acc[1][1] += a.y * b.y; acc[1][2] += a.y * b.z; acc[1][3] += a.y * b.w;
            acc[2][0] += a.z * b.x; acc[2][1] += a.z * b.y; acc[2][2] += a.z * b.z; acc[2][3] += a.z * b.w;
            acc[3][0] += a.w * b.x; acc[3][1] += a.w * b.y; acc[3][2] += a.w * b.z; acc[3][3] += a.w * b.w;
        }
        __syncthreads();
    }
#pragma unroll
    for (int i = 0; i < 4; ++i) {
        int row = bm + ty * 4 + i;
        if (row < Nrows) {
            float4 v = make_float4(acc[i][0], acc[i][1], acc[i][2], acc[i][3]);
            *reinterpret_cast<float4*>(C + (size_t)row * 256 + bn + tx * 4) = v;
        }
    }
}

// ------------- per-node attention logits: el/er [N,H] ------------------------
__global__ __launch_bounds__(256) void el_er_kernel(const float* __restrict__ feat,
                                                    const float* __restrict__ al,
                                                    const float* __restrict__ ar,
                                                    float* __restrict__ el,
                                                    float* __restrict__ er) {
    int n = blockIdx.x;
    int tid = threadIdx.x;            // h = tid>>6, d = tid&63
    float v = feat[(size_t)n * 256 + tid];
    float l = v * al[tid];
    float r = v * ar[tid];
    for (int off = 32; off; off >>= 1) {
        l += __shfl_down(l, off);
        r += __shfl_down(r, off);
    }
    if ((tid & 63) == 0) {
        int h = tid >> 6;
        el[n * 4 + h] = l;
        er[n * 4 + h] = r;
    }
}

// ================= CSR build (once per call, all 3 relations) ================
__global__ __launch_bounds__(256) void hist_kernel(const int* __restrict__ dst,
                                                   int* __restrict__ deg) {
    int i = blockIdx.x * 256 + threadIdx.x;
    if (i >= RR * EE) return;
    int r = i / EE;
    atomicAdd(&deg[r * NN + dst[i]], 1);
}

__global__ __launch_bounds__(256) void scan_block(const int* __restrict__ deg,
                                                  int* __restrict__ rowptr,
                                                  int* __restrict__ bsum) {
    __shared__ int sh[256];
    int r = blockIdx.y, b = blockIdx.x, t = threadIdx.x;
    int base = b * 1024;
    int v[4];
#pragma unroll
    for (int j = 0; j < 4; ++j) {
        int idx = base + t * 4 + j;
        v[j] = (idx < NN) ? deg[r * NN + idx] : 0;
    }
    int tsum = v[0] + v[1] + v[2] + v[3];
    sh[t] = tsum;
    __syncthreads();
    for (int off = 1; off < 256; off <<= 1) {
        int x = (t >= off) ? sh[t - off] : 0;
        __syncthreads();
        sh[t] += x;
        __syncthreads();
    }
    int run = sh[t] - tsum;   // exclusive prefix within block
#pragma unroll
    for (int j = 0; j < 4; ++j) {
        int idx = base + t * 4 + j;
        if (idx < NN) rowptr[r * (NN + 1) + idx] = run;
        run += v[j];
    }
    if (t == 255) bsum[r * NB + b] = run;
}

__global__ void scan_bsum(int* __restrict__ bsum, int* __restrict__ rowptr) {
    int r = threadIdx.x;
    if (r >= RR) return;
    int run = 0;
    for (int b = 0; b < NB; ++b) {
        int x = bsum[r * NB + b];
        bsum[r * NB + b] = run;
        run += x;
    }
    rowptr[r * (NN + 1) + NN] = run;   // == EE
}

__global__ __launch_bounds__(256) void add_off(int* __restrict__ rowptr,
                                               const int* __restrict__ bsum) {
    int r = blockIdx.y, b = blockIdx.x, t = threadIdx.x;
    int o = bsum[r * NB + b];
#pragma unroll
    for (int j = 0; j < 4; ++j) {
        int idx = b * 1024 + t * 4 + j;
        if (idx < NN) rowptr[r * (NN + 1) + idx] += o;
    }
}

__global__ __launch_bounds__(256) void fill_kernel(const int* __restrict__ src,
                                                   const int* __restrict__ dst,
                                                   const int* __restrict__ rowptr,
                                                   int* __restrict__ cursor,
                                                   int* __restrict__ csrc) {
    int i = blockIdx.x * 256 + threadIdx.x;
    if (i >= RR * EE) return;
    int r = i / EE;
    int d = dst[i], s = src[i];
    int pos = rowptr[r * (NN + 1) + d] + atomicAdd(&cursor[r * NN + d], 1);
    csrc[(size_t)r * EE + pos] = s;
}

// ========== fused edge-softmax + aggregation: one wave per dst node ==========
__global__ __launch_bounds__(256) void agg_kernel(const int* __restrict__ csrc,
                                                  const int* __restrict__ rowptr,
                                                  const float* __restrict__ el,
                                                  const float* __restrict__ er,
                                                  const float* __restrict__ feat,
                                                  float* __restrict__ acc) {
    int wid = (blockIdx.x * 256 + threadIdx.x) >> 6;
    int lane = threadIdx.x & 63;
    if (wid >= NN) return;
    int d = wid;
    int p0 = rowptr[d], p1 = rowptr[d + 1];
    if (p0 == p1) return;            // no edges: only bias (already in acc)
    int h = lane >> 4;               // this lane's head (lane*4 spans one head)
    float erd = er[d * 4 + h];
    float4 a = make_float4(0.f, 0.f, 0.f, 0.f);
    float zs = 0.f;
    for (int p = p0; p < p1; ++p) {
        int s = csrc[p];
        float v = el[s * 4 + h] + erd;
        v = v > 0.f ? v : 0.2f * v;
        float w = __expf(v);
        zs += w;
        float4 f = *reinterpret_cast<const float4*>(feat + (size_t)s * 256 + lane * 4);
        a.x += w * f.x; a.y += w * f.y; a.z += w * f.z; a.w += w * f.w;
    }
    float inv = 1.f / zs;
    float* ad = acc + (size_t)d * 256 + lane * 4;
    float4 cur = *reinterpret_cast<const float4*>(ad);
    cur.x += a.x * inv; cur.y += a.y * inv; cur.z += a.z * inv; cur.w += a.w * inv;
    *reinterpret_cast<float4*>(ad) = cur;
}

// ------------- acc init with summed per-relation bias ------------------------
__global__ __launch_bounds__(256) void bias_init(float* __restrict__ acc,
                                                 const float* __restrict__ b) {
    size_t idx = (size_t)blockIdx.x * 256 + threadIdx.x;
    if (idx >= (size_t)NN * 256) return;
    int f = idx & 255;
    acc[idx] = b[f] + b[256 + f] + b[512 + f];
}

__global__ __launch_bounds__(256) void relu_kernel(const float* __restrict__ in,
                                                   float* __restrict__ outp) {
    size_t idx = (size_t)blockIdx.x * 256 + threadIdx.x;
    if (idx >= (size_t)NN * 256) return;
    float v = in[idx];
    outp[idx] = v > 0.f ? v : 0.f;
}

// ------------- output linear: out[N,153] = H[N,256] @ Wout[256,153] + bout ---
__global__ __launch_bounds__(256) void out_gemm(const float* __restrict__ Hf,
                                                const float* __restrict__ Wout,
                                                const float* __restrict__ bout,
                                                float* __restrict__ outp, int Nrows) {
    __shared__ float sh[8][256];
    int n0 = blockIdx.x * 8;
    int tid = threadIdx.x;
#pragma unroll
    for (int i = 0; i < 8; ++i) {
        int n = n0 + i;
        sh[i][tid] = (n < Nrows) ? Hf[(size_t)n * 256 + tid] : 0.f;
    }
    __syncthreads();
    if (tid < CC) {
        float s[8] = {};
        for (int k = 0; k < 256; ++k) {
            float w = Wout[k * CC + tid];
#pragma unroll
            for (int i = 0; i < 8; ++i) s[i] += sh[i][k] * w;
        }
        float bb = bout[tid];
#pragma unroll
        for (int i = 0; i < 8; ++i) {
            int n = n0 + i;
            if (n < Nrows) outp[(size_t)n * CC + tid] = s[i] + bb;
        }
    }
}

extern "C" void kernel_launch(void* const* d_in, const int* in_sizes, int n_in,
                              void* d_out, int out_size, void* d_ws, size_t ws_size,
                              hipStream_t stream) {
    const float* x    = (const float*)d_in[0];
    const int*   src  = (const int*)d_in[1];
    const int*   dst  = (const int*)d_in[2];
    const float* W1   = (const float*)d_in[3];
    const float* al1  = (const float*)d_in[4];
    const float* ar1  = (const float*)d_in[5];
    const float* b1   = (const float*)d_in[6];
    const float* W2   = (const float*)d_in[7];
    const float* al2  = (const float*)d_in[8];
    const float* ar2  = (const float*)d_in[9];
    const float* b2   = (const float*)d_in[10];
    const float* Wout = (const float*)d_in[11];
    const float* bout = (const float*)d_in[12];
    float* out = (float*)d_out;

    // workspace layout: feat | h1 | acc | el | er | deg | cursor | rowptr | bsum | csrc
    float* ws = (float*)d_ws;
    size_t NF = (size_t)NN * HFF;
    float* feat = ws;
    float* h1   = ws + NF;
    float* acc  = ws + 2 * NF;
    float* el   = ws + 3 * NF;
    float* er   = el + (size_t)NN * NH;
    int* deg    = (int*)(er + (size_t)NN * NH);
    int* cursor = deg + (size_t)RR * NN;
    int* rowptr = cursor + (size_t)RR * NN;
    int* bsum   = rowptr + (size_t)RR * (NN + 1);
    int* csrc   = bsum + (size_t)RR * NB;

    dim3 ggrid((NN + 63) / 64, HFF / 64);
    int nfBlocks = (int)((NF + 255) / 256);
    int reBlocks = (RR * EE + 255) / 256;

    // ---- CSR build (shared by both layers) ----
    hipMemsetAsync(deg, 0, (size_t)RR * NN * sizeof(int) * 2, stream);  // deg + cursor
    hist_kernel<<<reBlocks, 256, 0, stream>>>(dst, deg);
    scan_block<<<dim3(NB, RR), 256, 0, stream>>>(deg, rowptr, bsum);
    scan_bsum<<<1, 64, 0, stream>>>(bsum, rowptr);
    add_off<<<dim3(NB, RR), 256, 0, stream>>>(rowptr, bsum);
    fill_kernel<<<reBlocks, 256, 0, stream>>>(src, dst, rowptr, cursor, csrc);

    for (int layer = 0; layer < 2; ++layer) {
        const float* X  = layer ? h1 : x;
        const float* W  = layer ? W2 : W1;
        const float* al = layer ? al2 : al1;
        const float* ar = layer ? ar2 : ar1;
        const float* b  = layer ? b2 : b1;

        bias_init<<<nfBlocks, 256, 0, stream>>>(acc, b);
        for (int r = 0; r < RR; ++r) {
            gemm64<<<ggrid, 256, 0, stream>>>(X, W + (size_t)r * INF * HFF, feat, NN);
            el_er_kernel<<<NN, 256, 0, stream>>>(feat, al + r * NH * DD, ar + r * NH * DD, el, er);
            agg_kernel<<<(NN * 64 + 255) / 256, 256, 0, stream>>>(
                csrc + (size_t)r * EE, rowptr + (size_t)r * (NN + 1), el, er, feat, acc);
        }
        if (layer == 0)
            relu_kernel<<<nfBlocks, 256, 0, stream>>>(acc, h1);
    }
    out_gemm<<<(NN + 7) / 8, 256, 0, stream>>>(acc, Wout, bout, out, NN);
}

// Round 6
// 1729.889 us; speedup vs baseline: 2.7718x; 1.5133x over previous
//
#include <hip/hip_runtime.h>
#include <hip/hip_bf16.h>

#define NN 100000
#define EE 600000
#define RR 3
#define INF 256
#define HFF 256
#define NH 4
#define DD 64
#define CC 153
#define NB 98   // ceil(NN/1024)

typedef __attribute__((ext_vector_type(8))) _Float16 f16x8;
typedef __attribute__((ext_vector_type(4))) float f32x4;

#define GLDS(g, l) __builtin_amdgcn_global_load_lds((const __attribute__((address_space(1))) void*)(g), \
                                                    (__attribute__((address_space(3))) void*)(l), 16, 0, 0)

static __device__ __forceinline__ unsigned short f2h(float x) {
    _Float16 h = (_Float16)x;                 // v_cvt_f16_f32, RNE
    return __builtin_bit_cast(unsigned short, h);
}

// ================= f16 MFMA GEMM: C[M,ldc] = A[M,256](f16) @ Bt[n][k](f16) [+ bias[n]]
// 128x128 tile, BK=64, 4 waves (2x2), 16x16x32 MFMA, global_load_lds staging,
// XOR-swizzled LDS (byte ^= (row&7)<<4 within 128B rows).
__global__ __launch_bounds__(256) void mfma_gemm(const unsigned short* __restrict__ A,
                                                 const unsigned short* __restrict__ Bt,
                                                 const float* __restrict__ bias,
                                                 float* __restrict__ C,
                                                 int M, int ldc, int colmax) {
    __shared__ __align__(1024) char lds[32768];   // A tile 16KB | B tile 16KB
    const int tid = threadIdx.x;
    const int lane = tid & 63;
    const int w = tid >> 6;
    const int wr = w >> 1, wc = w & 1;
    const int bm = blockIdx.x * 128;
    const int bn = blockIdx.y * 128;

    f32x4 acc[4][4] = {};

    const int lrow8 = lane >> 3;                 // 0..7
    const int cbs = ((lane & 7) << 4) ^ ((lrow8 & 7) << 4);  // swizzled within-row byte
    const int cbase = w * 8;                     // this wave's chunk base (0,8,16,24)
    const bool isA = (w < 2);

    const char* gA = (const char*)A;
    const char* gB = (const char*)Bt;

    for (int step = 0; step < 4; ++step) {
        const int k0b = step * 128;              // 64 f16 per K-step
#pragma unroll
        for (int i = 0; i < 8; ++i) {
            int c = cbase + i;                   // chunk 0..31 (1 KB each)
            char* lptr = &lds[c * 1024];
            if (isA) {
                int R = c * 8 + lrow8;           // LDS row 0..127
                int grow = bm + R; if (grow >= M) grow = M - 1;
                GLDS(gA + (size_t)grow * 512 + k0b + cbs, lptr);
            } else {
                int nIdx = (c - 16) * 8 + lrow8; // 0..127
                GLDS(gB + (size_t)(bn + nIdx) * 512 + k0b + cbs, lptr);
            }
        }
        __syncthreads();
#pragma unroll
        for (int kk = 0; kk < 2; ++kk) {
            f16x8 af[4], bfr[4];
            const int o = kk * 64 + ((lane >> 4) << 4);
#pragma unroll
            for (int m = 0; m < 4; ++m) {
                int R = wr * 64 + m * 16 + (lane & 15);
                af[m] = *reinterpret_cast<const f16x8*>(&lds[R * 128 + (o ^ ((R & 7) << 4))]);
            }
#pragma unroll
            for (int n = 0; n < 4; ++n) {
                int Rn = wc * 64 + n * 16 + (lane & 15);
                bfr[n] = *reinterpret_cast<const f16x8*>(&lds[16384 + Rn * 128 + (o ^ ((Rn & 7) << 4))]);
            }
#pragma unroll
            for (int m = 0; m < 4; ++m)
#pragma unroll
                for (int n = 0; n < 4; ++n)
                    acc[m][n] = __builtin_amdgcn_mfma_f32_16x16x32_f16(af[m], bfr[n], acc[m][n], 0, 0, 0);
        }
        __syncthreads();
    }
    const int rb = bm + wr * 64 + ((lane >> 4) << 2);
    const int cb2 = bn + wc * 64 + (lane & 15);
#pragma unroll
    for (int m = 0; m < 4; ++m)
#pragma unroll
        for (int n = 0; n < 4; ++n) {
            int col = cb2 + n * 16;
            if (col < colmax) {
                float bb = bias ? bias[col] : 0.f;
#pragma unroll
                for (int j = 0; j < 4; ++j) {
                    int row = rb + m * 16 + j;
                    if (row < M) C[(size_t)row * ldc + col] = acc[m][n][j] + bb;
                }
            }
        }
}

// ------------- conversions --------------------------------------------------
__global__ __launch_bounds__(256) void f2h4(const float* __restrict__ in,
                                            unsigned short* __restrict__ out, int n4) {
    int i = blockIdx.x * 256 + threadIdx.x;
    if (i >= n4) return;
    float4 v = reinterpret_cast<const float4*>(in)[i];
    ushort4 o;
    o.x = f2h(v.x); o.y = f2h(v.y); o.z = f2h(v.z); o.w = f2h(v.w);
    reinterpret_cast<ushort4*>(out)[i] = o;
}

__global__ __launch_bounds__(256) void relu_f2h4(const float* __restrict__ in,
                                                 unsigned short* __restrict__ out, int n4) {
    int i = blockIdx.x * 256 + threadIdx.x;
    if (i >= n4) return;
    float4 v = reinterpret_cast<const float4*>(in)[i];
    ushort4 o;
    o.x = f2h(fmaxf(v.x, 0.f)); o.y = f2h(fmaxf(v.y, 0.f));
    o.z = f2h(fmaxf(v.z, 0.f)); o.w = f2h(fmaxf(v.w, 0.f));
    reinterpret_cast<ushort4*>(out)[i] = o;
}

// Wt[r][n][k] = f16(W[r][k][n])
__global__ __launch_bounds__(256) void wt_kernel(const float* __restrict__ W,
                                                 unsigned short* __restrict__ Wt) {
    int idx = blockIdx.x * 256 + threadIdx.x;
    if (idx >= RR * 65536) return;
    int r = idx >> 16, rem = idx & 65535;
    int n = rem >> 8, k = rem & 255;
    Wt[idx] = f2h(W[(r << 16) + (k << 8) + n]);
}

// Woutt[n][k] = f16(Wout[k][n]) padded to n<256 with zeros
__global__ __launch_bounds__(256) void wout_kernel(const float* __restrict__ Wout,
                                                   unsigned short* __restrict__ Wt) {
    int idx = blockIdx.x * 256 + threadIdx.x;
    if (idx >= 65536) return;
    int n = idx >> 8, k = idx & 255;
    Wt[idx] = (n < CC) ? f2h(Wout[k * CC + n]) : (unsigned short)0;
}

// ------------- per-node attention logits: el/er [N,H] ------------------------
__global__ __launch_bounds__(256) void el_er_kernel(const float* __restrict__ feat,
                                                    const float* __restrict__ al,
                                                    const float* __restrict__ ar,
                                                    float* __restrict__ el,
                                                    float* __restrict__ er) {
    int n = blockIdx.x;
    int tid = threadIdx.x;
    float v = feat[(size_t)n * 256 + tid];
    float l = v * al[tid];
    float r = v * ar[tid];
    for (int off = 32; off; off >>= 1) {
        l += __shfl_down(l, off);
        r += __shfl_down(r, off);
    }
    if ((tid & 63) == 0) {
        int h = tid >> 6;
        el[n * 4 + h] = l;
        er[n * 4 + h] = r;
    }
}

// ================= CSR build (once per call, all 3 relations) ================
__global__ __launch_bounds__(256) void hist_kernel(const int* __restrict__ dst,
                                                   int* __restrict__ deg) {
    int i = blockIdx.x * 256 + threadIdx.x;
    if (i >= RR * EE) return;
    int r = i / EE;
    atomicAdd(&deg[r * NN + dst[i]], 1);
}

__global__ __launch_bounds__(256) void scan_block(const int* __restrict__ deg,
                                                  int* __restrict__ rowptr,
                                                  int* __restrict__ bsum) {
    __shared__ int sh[256];
    int r = blockIdx.y, b = blockIdx.x, t = threadIdx.x;
    int base = b * 1024;
    int v[4];
#pragma unroll
    for (int j = 0; j < 4; ++j) {
        int idx = base + t * 4 + j;
        v[j] = (idx < NN) ? deg[r * NN + idx] : 0;
    }
    int tsum = v[0] + v[1] + v[2] + v[3];
    sh[t] = tsum;
    __syncthreads();
    for (int off = 1; off < 256; off <<= 1) {
        int x = (t >= off) ? sh[t - off] : 0;
        __syncthreads();
        sh[t] += x;
        __syncthreads();
    }
    int run = sh[t] - tsum;
#pragma unroll
    for (int j = 0; j < 4; ++j) {
        int idx = base + t * 4 + j;
        if (idx < NN) rowptr[r * (NN + 1) + idx] = run;
        run += v[j];
    }
    if (t == 255) bsum[r * NB + b] = run;
}

__global__ void scan_bsum(int* __restrict__ bsum, int* __restrict__ rowptr) {
    int r = threadIdx.x;
    if (r >= RR) return;
    int run = 0;
    for (int b = 0; b < NB; ++b) {
        int x = bsum[r * NB + b];
        bsum[r * NB + b] = run;
        run += x;
    }
    rowptr[r * (NN + 1) + NN] = run;
}

__global__ __launch_bounds__(256) void add_off(int* __restrict__ rowptr,
                                               const int* __restrict__ bsum) {
    int r = blockIdx.y, b = blockIdx.x, t = threadIdx.x;
    int o = bsum[r * NB + b];
#pragma unroll
    for (int j = 0; j < 4; ++j) {
        int idx = b * 1024 + t * 4 + j;
        if (idx < NN) rowptr[r * (NN + 1) + idx] += o;
    }
}

__global__ __launch_bounds__(256) void fill_kernel(const int* __restrict__ src,
                                                   const int* __restrict__ dst,
                                                   const int* __restrict__ rowptr,
                                                   int* __restrict__ cursor,
                                                   int* __restrict__ csrc) {
    int i = blockIdx.x * 256 + threadIdx.x;
    if (i >= RR * EE) return;
    int r = i / EE;
    int d = dst[i], s = src[i];
    int pos = rowptr[r * (NN + 1) + d] + atomicAdd(&cursor[r * NN + d], 1);
    csrc[(size_t)r * EE + pos] = s;
}

// ========== fused edge-softmax + aggregation: one wave per dst node ==========
__global__ __launch_bounds__(256) void agg_kernel(const int* __restrict__ csrc,
                                                  const int* __restrict__ rowptr,
                                                  const float* __restrict__ el,
                                                  const float* __restrict__ er,
                                                  const float* __restrict__ feat,
                                                  float* __restrict__ acc) {
    int wid = (blockIdx.x * 256 + threadIdx.x) >> 6;
    int lane = threadIdx.x & 63;
    if (wid >= NN) return;
    int d = wid;
    int p0 = rowptr[d], p1 = rowptr[d + 1];
    if (p0 == p1) return;
    int h = lane >> 4;
    float erd = er[d * 4 + h];
    float4 a = make_float4(0.f, 0.f, 0.f, 0.f);
    float zs = 0.f;
    for (int p = p0; p < p1; ++p) {
        int s = csrc[p];
        float v = el[s * 4 + h] + erd;
        v = v > 0.f ? v : 0.2f * v;
        float wgt = __expf(v);
        zs += wgt;
        float4 f = *reinterpret_cast<const float4*>(feat + (size_t)s * 256 + lane * 4);
        a.x += wgt * f.x; a.y += wgt * f.y; a.z += wgt * f.z; a.w += wgt * f.w;
    }
    float inv = 1.f / zs;
    float* ad = acc + (size_t)d * 256 + lane * 4;
    float4 cur = *reinterpret_cast<const float4*>(ad);
    cur.x += a.x * inv; cur.y += a.y * inv; cur.z += a.z * inv; cur.w += a.w * inv;
    *reinterpret_cast<float4*>(ad) = cur;
}

__global__ __launch_bounds__(256) void bias_init(float* __restrict__ acc,
                                                 const float* __restrict__ b) {
    size_t idx = (size_t)blockIdx.x * 256 + threadIdx.x;
    if (idx >= (size_t)NN * 256) return;
    int f = idx & 255;
    acc[idx] = b[f] + b[256 + f] + b[512 + f];
}

extern "C" void kernel_launch(void* const* d_in, const int* in_sizes, int n_in,
                              void* d_out, int out_size, void* d_ws, size_t ws_size,
                              hipStream_t stream) {
    const float* x    = (const float*)d_in[0];
    const int*   src  = (const int*)d_in[1];
    const int*   dst  = (const int*)d_in[2];
    const float* W1   = (const float*)d_in[3];
    const float* al1  = (const float*)d_in[4];
    const float* ar1  = (const float*)d_in[5];
    const float* b1   = (const float*)d_in[6];
    const float* W2   = (const float*)d_in[7];
    const float* al2  = (const float*)d_in[8];
    const float* ar2  = (const float*)d_in[9];
    const float* b2   = (const float*)d_in[10];
    const float* Wout = (const float*)d_in[11];
    const float* bout = (const float*)d_in[12];
    float* out = (float*)d_out;

    // ---- workspace layout: every sub-buffer 256B-aligned ----
    char* base = (char*)d_ws;
    size_t off = 0;
    auto alloc = [&](size_t bytes) -> char* {
        char* p = base + off;
        off = (off + bytes + 255) & ~(size_t)255;
        return p;
    };
    size_t NF = (size_t)NN * HFF;                 // 25.6M elements
    float* feat = (float*)alloc(NF * 4);
    float* acc  = (float*)alloc(NF * 4);
    float* el   = (float*)alloc((size_t)NN * NH * 4);
    float* er   = (float*)alloc((size_t)NN * NH * 4);
    int* deg    = (int*)alloc((size_t)RR * NN * 4 * 2);   // deg + cursor contiguous
    int* cursor = deg + (size_t)RR * NN;
    int* rowptr = (int*)alloc((size_t)RR * (NN + 1) * 4);
    int* bsum   = (int*)alloc((size_t)RR * NB * 4);
    int* csrc   = (int*)alloc((size_t)RR * EE * 4);
    unsigned short* xh    = (unsigned short*)alloc(NF * 2);          // x_f16 / h1_f16 / h2_f16
    unsigned short* wth   = (unsigned short*)alloc((size_t)RR * 65536 * 2);
    unsigned short* wouth = (unsigned short*)alloc((size_t)65536 * 2);

    int nfBlocks = (int)((NF + 255) / 256);
    int n4Blocks = (int)((NF / 4 + 255) / 256);
    int reBlocks = (RR * EE + 255) / 256;
    dim3 ggrid((NN + 127) / 128, 2);

    // ---- CSR build (shared by both layers) ----
    hipMemsetAsync(deg, 0, (size_t)RR * NN * sizeof(int) * 2, stream);
    hist_kernel<<<reBlocks, 256, 0, stream>>>(dst, deg);
    scan_block<<<dim3(NB, RR), 256, 0, stream>>>(deg, rowptr, bsum);
    scan_bsum<<<1, 64, 0, stream>>>(bsum, rowptr);
    add_off<<<dim3(NB, RR), 256, 0, stream>>>(rowptr, bsum);
    fill_kernel<<<reBlocks, 256, 0, stream>>>(src, dst, rowptr, cursor, csrc);

    // ---- input conversion ----
    f2h4<<<n4Blocks, 256, 0, stream>>>(x, xh, (int)(NF / 4));

    for (int layer = 0; layer < 2; ++layer) {
        const float* W  = layer ? W2 : W1;
        const float* al = layer ? al2 : al1;
        const float* ar = layer ? ar2 : ar1;
        const float* b  = layer ? b2 : b1;

        wt_kernel<<<(RR * 65536) / 256, 256, 0, stream>>>(W, wth);
        bias_init<<<nfBlocks, 256, 0, stream>>>(acc, b);
        for (int r = 0; r < RR; ++r) {
            mfma_gemm<<<ggrid, 256, 0, stream>>>(xh, wth + (size_t)r * 65536, nullptr, feat, NN, HFF, HFF);
            el_er_kernel<<<NN, 256, 0, stream>>>(feat, al + r * NH * DD, ar + r * NH * DD, el, er);
            agg_kernel<<<(NN * 64 + 255) / 256, 256, 0, stream>>>(
                csrc + (size_t)r * EE, rowptr + (size_t)r * (NN + 1), el, er, feat, acc);
        }
        if (layer == 0)
            relu_f2h4<<<n4Blocks, 256, 0, stream>>>(acc, xh, (int)(NF / 4));
    }

    // ---- output linear (+ bout) ----
    f2h4<<<n4Blocks, 256, 0, stream>>>(acc, xh, (int)(NF / 4));
    wout_kernel<<<65536 / 256, 256, 0, stream>>>(Wout, wouth);
    mfma_gemm<<<ggrid, 256, 0, stream>>>(xh, wouth, bout, out, NN, CC, CC);
}

// Round 7
// 1076.174 us; speedup vs baseline: 4.4556x; 1.6074x over previous
//
#include <hip/hip_runtime.h>
#include <hip/hip_bf16.h>

#define NN 100000
#define EE 600000
#define RR 3
#define INF 256
#define HFF 256
#define NH 4
#define DD 64
#define CC 153
#define NB 98   // ceil(NN/1024)

typedef __attribute__((ext_vector_type(8))) _Float16 f16x8;
typedef __attribute__((ext_vector_type(4))) float f32x4;

#define GLDS(g, l) __builtin_amdgcn_global_load_lds((const __attribute__((address_space(1))) void*)(g), \
                                                    (__attribute__((address_space(3))) void*)(l), 16, 0, 0)

static __device__ __forceinline__ unsigned short f2h(float x) {
    _Float16 h = (_Float16)x;
    return __builtin_bit_cast(unsigned short, h);
}
static __device__ __forceinline__ float h2f(unsigned short u) {
    return (float)__builtin_bit_cast(_Float16, u);
}

// ================= f16 MFMA GEMM, 128x128 tile, BK=64, 4 waves ================
// GM=0: C32[M,CC] = A@Bt + bias  (final linear)
// GM=1: C16[M,256] = f16(A@Bt); fused el/er epilogue (each wave owns one head
//       for its 64 rows -> in-register dot + 16-lane shfl reduce, no atomics)
template<int GM>
__global__ __launch_bounds__(256) void mfma_gemm(const unsigned short* __restrict__ A,
                                                 const unsigned short* __restrict__ Bt,
                                                 const float* __restrict__ bias,
                                                 float* __restrict__ C32,
                                                 unsigned short* __restrict__ C16,
                                                 const float* __restrict__ al,
                                                 const float* __restrict__ ar,
                                                 float* __restrict__ el,
                                                 float* __restrict__ er,
                                                 int M) {
    __shared__ __align__(1024) char lds[32768];   // A tile 16KB | B tile 16KB
    const int tid = threadIdx.x;
    const int lane = tid & 63;
    const int w = tid >> 6;
    const int wr = w >> 1, wc = w & 1;
    const int bm = blockIdx.x * 128;
    const int bn = blockIdx.y * 128;

    f32x4 acc[4][4] = {};

    const int lrow8 = lane >> 3;
    const int cbs = ((lane & 7) << 4) ^ ((lrow8 & 7) << 4);
    const int cbase = w * 8;
    const bool isA = (w < 2);

    const char* gA = (const char*)A;
    const char* gB = (const char*)Bt;

    for (int step = 0; step < 4; ++step) {
        const int k0b = step * 128;              // 64 f16 per K-step
#pragma unroll
        for (int i = 0; i < 8; ++i) {
            int c = cbase + i;
            char* lptr = &lds[c * 1024];
            if (isA) {
                int R = c * 8 + lrow8;
                int grow = bm + R; if (grow >= M) grow = M - 1;
                GLDS(gA + (size_t)grow * 512 + k0b + cbs, lptr);
            } else {
                int nIdx = (c - 16) * 8 + lrow8;
                GLDS(gB + (size_t)(bn + nIdx) * 512 + k0b + cbs, lptr);
            }
        }
        __syncthreads();
#pragma unroll
        for (int kk = 0; kk < 2; ++kk) {
            f16x8 af[4], bfr[4];
            const int o = kk * 64 + ((lane >> 4) << 4);
#pragma unroll
            for (int m = 0; m < 4; ++m) {
                int R = wr * 64 + m * 16 + (lane & 15);
                af[m] = *reinterpret_cast<const f16x8*>(&lds[R * 128 + (o ^ ((R & 7) << 4))]);
            }
#pragma unroll
            for (int n = 0; n < 4; ++n) {
                int Rn = wc * 64 + n * 16 + (lane & 15);
                bfr[n] = *reinterpret_cast<const f16x8*>(&lds[16384 + Rn * 128 + (o ^ ((Rn & 7) << 4))]);
            }
#pragma unroll
            for (int m = 0; m < 4; ++m)
#pragma unroll
                for (int n = 0; n < 4; ++n)
                    acc[m][n] = __builtin_amdgcn_mfma_f32_16x16x32_f16(af[m], bfr[n], acc[m][n], 0, 0, 0);
        }
        __syncthreads();
    }

    const int rb = bm + wr * 64 + ((lane >> 4) << 2);

    if (GM == 0) {
        const int cb2 = bn + wc * 64 + (lane & 15);
#pragma unroll
        for (int m = 0; m < 4; ++m)
#pragma unroll
            for (int n = 0; n < 4; ++n) {
                int col = cb2 + n * 16;
                if (col < CC) {
                    float bb = bias[col];
#pragma unroll
                    for (int j = 0; j < 4; ++j) {
                        int row = rb + m * 16 + j;
                        if (row < M) C32[(size_t)row * CC + col] = acc[m][n][j] + bb;
                    }
                }
            }
    } else {
        // ---- fused el/er: this wave's 64 cols == one full head h ----
        const int h = (bn >> 6) + wc;
        float alv[4], arv[4];
#pragma unroll
        for (int n = 0; n < 4; ++n) {
            alv[n] = al[h * 64 + n * 16 + (lane & 15)];
            arv[n] = ar[h * 64 + n * 16 + (lane & 15)];
        }
#pragma unroll
        for (int m = 0; m < 4; ++m)
#pragma unroll
            for (int j = 0; j < 4; ++j) {
                float pl = acc[m][0][j] * alv[0] + acc[m][1][j] * alv[1]
                         + acc[m][2][j] * alv[2] + acc[m][3][j] * alv[3];
                float pr = acc[m][0][j] * arv[0] + acc[m][1][j] * arv[1]
                         + acc[m][2][j] * arv[2] + acc[m][3][j] * arv[3];
#pragma unroll
                for (int o2 = 1; o2 < 16; o2 <<= 1) {
                    pl += __shfl_xor(pl, o2);
                    pr += __shfl_xor(pr, o2);
                }
                int row = rb + m * 16 + j;
                if ((lane & 15) == 0 && row < M) {
                    el[row * 4 + h] = pl;
                    er[row * 4 + h] = pr;
                }
            }
        // ---- fp16 feat store ----
        const int cb2 = bn + wc * 64 + (lane & 15);
#pragma unroll
        for (int m = 0; m < 4; ++m)
#pragma unroll
            for (int n = 0; n < 4; ++n) {
                int col = cb2 + n * 16;
#pragma unroll
                for (int j = 0; j < 4; ++j) {
                    int row = rb + m * 16 + j;
                    if (row < M) C16[(size_t)row * 256 + col] = f2h(acc[m][n][j]);
                }
            }
    }
}

// ------------- conversions --------------------------------------------------
__global__ __launch_bounds__(256) void f2h4(const float* __restrict__ in,
                                            unsigned short* __restrict__ out, int n4) {
    int i = blockIdx.x * 256 + threadIdx.x;
    if (i >= n4) return;
    float4 v = reinterpret_cast<const float4*>(in)[i];
    ushort4 o;
    o.x = f2h(v.x); o.y = f2h(v.y); o.z = f2h(v.z); o.w = f2h(v.w);
    reinterpret_cast<ushort4*>(out)[i] = o;
}

// Wt[r][n][k] = f16(W[r][k][n])
__global__ __launch_bounds__(256) void wt_kernel(const float* __restrict__ W,
                                                 unsigned short* __restrict__ Wt) {
    int idx = blockIdx.x * 256 + threadIdx.x;
    if (idx >= RR * 65536) return;
    int r = idx >> 16, rem = idx & 65535;
    int n = rem >> 8, k = rem & 255;
    Wt[idx] = f2h(W[(r << 16) + (k << 8) + n]);
}

// Woutt[n][k] = f16(Wout[k][n]) padded to n<256 with zeros
__global__ __launch_bounds__(256) void wout_kernel(const float* __restrict__ Wout,
                                                   unsigned short* __restrict__ Wt) {
    int idx = blockIdx.x * 256 + threadIdx.x;
    if (idx >= 65536) return;
    int n = idx >> 8, k = idx & 255;
    Wt[idx] = (n < CC) ? f2h(Wout[k * CC + n]) : (unsigned short)0;
}

// ================= CSR build (once per call, all 3 relations) ================
__global__ __launch_bounds__(256) void hist_kernel(const int* __restrict__ dst,
                                                   int* __restrict__ deg) {
    int i = blockIdx.x * 256 + threadIdx.x;
    if (i >= RR * EE) return;
    int r = i / EE;
    atomicAdd(&deg[r * NN + dst[i]], 1);
}

__global__ __launch_bounds__(256) void scan_block(const int* __restrict__ deg,
                                                  int* __restrict__ rowptr,
                                                  int* __restrict__ bsum) {
    __shared__ int sh[256];
    int r = blockIdx.y, b = blockIdx.x, t = threadIdx.x;
    int base = b * 1024;
    int v[4];
#pragma unroll
    for (int j = 0; j < 4; ++j) {
        int idx = base + t * 4 + j;
        v[j] = (idx < NN) ? deg[r * NN + idx] : 0;
    }
    int tsum = v[0] + v[1] + v[2] + v[3];
    sh[t] = tsum;
    __syncthreads();
    for (int off = 1; off < 256; off <<= 1) {
        int x = (t >= off) ? sh[t - off] : 0;
        __syncthreads();
        sh[t] += x;
        __syncthreads();
    }
    int run = sh[t] - tsum;
#pragma unroll
    for (int j = 0; j < 4; ++j) {
        int idx = base + t * 4 + j;
        if (idx < NN) rowptr[r * (NN + 1) + idx] = run;
        run += v[j];
    }
    if (t == 255) bsum[r * NB + b] = run;
}

__global__ void scan_bsum(int* __restrict__ bsum, int* __restrict__ rowptr) {
    int r = threadIdx.x;
    if (r >= RR) return;
    int run = 0;
    for (int b = 0; b < NB; ++b) {
        int x = bsum[r * NB + b];
        bsum[r * NB + b] = run;
        run += x;
    }
    rowptr[r * (NN + 1) + NN] = run;
}

__global__ __launch_bounds__(256) void add_off(int* __restrict__ rowptr,
                                               const int* __restrict__ bsum) {
    int r = blockIdx.y, b = blockIdx.x, t = threadIdx.x;
    int o = bsum[r * NB + b];
#pragma unroll
    for (int j = 0; j < 4; ++j) {
        int idx = b * 1024 + t * 4 + j;
        if (idx < NN) rowptr[r * (NN + 1) + idx] += o;
    }
}

__global__ __launch_bounds__(256) void fill_kernel(const int* __restrict__ src,
                                                   const int* __restrict__ dst,
                                                   const int* __restrict__ rowptr,
                                                   int* __restrict__ cursor,
                                                   int* __restrict__ csrc) {
    int i = blockIdx.x * 256 + threadIdx.x;
    if (i >= RR * EE) return;
    int r = i / EE;
    int d = dst[i], s = src[i];
    int pos = rowptr[r * (NN + 1) + d] + atomicAdd(&cursor[r * NN + d], 1);
    csrc[(size_t)r * EE + pos] = s;
}

// ========== fused edge-softmax + aggregation: one wave per dst node ==========
// MODE 0: r=0 — init cur from summed relation bias (all rows), write acc
// MODE 1: r=1 — RMW acc (early-exit on zero-degree rows)
// MODE 2: r=2, layer 0 — read acc, add, relu, write fp16 to hout
// MODE 3: r=2, layer 1 — read acc, add, write fp16 to hout
template<int MODE>
__global__ __launch_bounds__(256) void agg_kernel(const int* __restrict__ csrc,
                                                  const int* __restrict__ rowptr,
                                                  const float* __restrict__ el,
                                                  const float* __restrict__ er,
                                                  const unsigned short* __restrict__ feat,
                                                  float* __restrict__ acc,
                                                  const float* __restrict__ brel,
                                                  unsigned short* __restrict__ hout) {
    int wid = (blockIdx.x * 256 + threadIdx.x) >> 6;
    int lane = threadIdx.x & 63;
    if (wid >= NN) return;
    int d = wid;
    int p0 = rowptr[d], p1 = rowptr[d + 1];
    if (MODE == 1 && p0 == p1) return;
    int h = lane >> 4;
    float erd = er[d * 4 + h];
    float4 a = make_float4(0.f, 0.f, 0.f, 0.f);
    float zs = 0.f;
    for (int p = p0; p < p1; ++p) {
        int s = csrc[p];
        float v = el[s * 4 + h] + erd;
        v = v > 0.f ? v : 0.2f * v;
        float wgt = __expf(v);
        zs += wgt;
        ushort4 f = *reinterpret_cast<const ushort4*>(feat + (size_t)s * 256 + lane * 4);
        a.x += wgt * h2f(f.x); a.y += wgt * h2f(f.y);
        a.z += wgt * h2f(f.z); a.w += wgt * h2f(f.w);
    }
    int f0 = lane * 4;
    float4 cur;
    if (MODE == 0) {
        float4 bA = *reinterpret_cast<const float4*>(brel + f0);
        float4 bB = *reinterpret_cast<const float4*>(brel + 256 + f0);
        float4 bC = *reinterpret_cast<const float4*>(brel + 512 + f0);
        cur = make_float4(bA.x + bB.x + bC.x, bA.y + bB.y + bC.y,
                          bA.z + bB.z + bC.z, bA.w + bB.w + bC.w);
    } else {
        cur = *reinterpret_cast<const float4*>(acc + (size_t)d * 256 + f0);
    }
    if (p1 > p0) {
        float inv = 1.f / zs;
        cur.x += a.x * inv; cur.y += a.y * inv;
        cur.z += a.z * inv; cur.w += a.w * inv;
    }
    if (MODE <= 1) {
        *reinterpret_cast<float4*>(acc + (size_t)d * 256 + f0) = cur;
    } else {
        if (MODE == 2) {
            cur.x = fmaxf(cur.x, 0.f); cur.y = fmaxf(cur.y, 0.f);
            cur.z = fmaxf(cur.z, 0.f); cur.w = fmaxf(cur.w, 0.f);
        }
        ushort4 o;
        o.x = f2h(cur.x); o.y = f2h(cur.y); o.z = f2h(cur.z); o.w = f2h(cur.w);
        *reinterpret_cast<ushort4*>(hout + (size_t)d * 256 + f0) = o;
    }
}

extern "C" void kernel_launch(void* const* d_in, const int* in_sizes, int n_in,
                              void* d_out, int out_size, void* d_ws, size_t ws_size,
                              hipStream_t stream) {
    const float* x    = (const float*)d_in[0];
    const int*   src  = (const int*)d_in[1];
    const int*   dst  = (const int*)d_in[2];
    const float* W1   = (const float*)d_in[3];
    const float* al1  = (const float*)d_in[4];
    const float* ar1  = (const float*)d_in[5];
    const float* b1   = (const float*)d_in[6];
    const float* W2   = (const float*)d_in[7];
    const float* al2  = (const float*)d_in[8];
    const float* ar2  = (const float*)d_in[9];
    const float* b2   = (const float*)d_in[10];
    const float* Wout = (const float*)d_in[11];
    const float* bout = (const float*)d_in[12];
    float* out = (float*)d_out;

    // ---- workspace layout: every sub-buffer 256B-aligned ----
    char* base = (char*)d_ws;
    size_t off = 0;
    auto alloc = [&](size_t bytes) -> char* {
        char* p = base + off;
        off = (off + bytes + 255) & ~(size_t)255;
        return p;
    };
    size_t NF = (size_t)NN * HFF;                 // 25.6M elements
    unsigned short* feath = (unsigned short*)alloc(NF * 2);   // fp16 projected feat
    float* acc  = (float*)alloc(NF * 4);
    float* el   = (float*)alloc((size_t)NN * NH * 4);
    float* er   = (float*)alloc((size_t)NN * NH * 4);
    int* deg    = (int*)alloc((size_t)RR * NN * 4 * 2);       // deg + cursor contiguous
    int* cursor = deg + (size_t)RR * NN;
    int* rowptr = (int*)alloc((size_t)RR * (NN + 1) * 4);
    int* bsum   = (int*)alloc((size_t)RR * NB * 4);
    int* csrc   = (int*)alloc((size_t)RR * EE * 4);
    unsigned short* xh    = (unsigned short*)alloc(NF * 2);   // x_f16 / h1_f16 / h2_f16
    unsigned short* wth   = (unsigned short*)alloc((size_t)RR * 65536 * 2);
    unsigned short* wouth = (unsigned short*)alloc((size_t)65536 * 2);

    int n4Blocks = (int)((NF / 4 + 255) / 256);
    int reBlocks = (RR * EE + 255) / 256;
    int aggBlocks = (NN * 64 + 255) / 256;
    dim3 ggrid((NN + 127) / 128, 2);

    // ---- CSR build (shared by both layers) ----
    hipMemsetAsync(deg, 0, (size_t)RR * NN * sizeof(int) * 2, stream);
    hist_kernel<<<reBlocks, 256, 0, stream>>>(dst, deg);
    scan_block<<<dim3(NB, RR), 256, 0, stream>>>(deg, rowptr, bsum);
    scan_bsum<<<1, 64, 0, stream>>>(bsum, rowptr);
    add_off<<<dim3(NB, RR), 256, 0, stream>>>(rowptr, bsum);
    fill_kernel<<<reBlocks, 256, 0, stream>>>(src, dst, rowptr, cursor, csrc);

    // ---- input conversion ----
    f2h4<<<n4Blocks, 256, 0, stream>>>(x, xh, (int)(NF / 4));

    for (int layer = 0; layer < 2; ++layer) {
        const float* W  = layer ? W2 : W1;
        const float* al = layer ? al2 : al1;
        const float* ar = layer ? ar2 : ar1;
        const float* b  = layer ? b2 : b1;

        wt_kernel<<<(RR * 65536) / 256, 256, 0, stream>>>(W, wth);
        for (int r = 0; r < RR; ++r) {
            mfma_gemm<1><<<ggrid, 256, 0, stream>>>(xh, wth + (size_t)r * 65536, nullptr,
                                                    nullptr, feath,
                                                    al + r * NH * DD, ar + r * NH * DD,
                                                    el, er, NN);
            const int* cs = csrc + (size_t)r * EE;
            const int* rp = rowptr + (size_t)r * (NN + 1);
            if (r == 0)
                agg_kernel<0><<<aggBlocks, 256, 0, stream>>>(cs, rp, el, er, feath, acc, b, nullptr);
            else if (r == 1)
                agg_kernel<1><<<aggBlocks, 256, 0, stream>>>(cs, rp, el, er, feath, acc, nullptr, nullptr);
            else if (layer == 0)
                agg_kernel<2><<<aggBlocks, 256, 0, stream>>>(cs, rp, el, er, feath, acc, nullptr, xh);
            else
                agg_kernel<3><<<aggBlocks, 256, 0, stream>>>(cs, rp, el, er, feath, acc, nullptr, xh);
        }
    }

    // ---- output linear (+ bout) ----
    wout_kernel<<<65536 / 256, 256, 0, stream>>>(Wout, wouth);
    mfma_gemm<0><<<ggrid, 256, 0, stream>>>(xh, wouth, bout, out, nullptr,
                                            nullptr, nullptr, nullptr, nullptr, NN);
}

// Round 8
// 982.921 us; speedup vs baseline: 4.8783x; 1.0949x over previous
//
#include <hip/hip_runtime.h>
#include <hip/hip_bf16.h>

#define NN 100000
#define EE 600000
#define RR 3
#define INF 256
#define HFF 256
#define NH 4
#define DD 64
#define CC 153
#define NB 98   // ceil(NN/1024)

typedef __attribute__((ext_vector_type(8))) _Float16 f16x8;
typedef __attribute__((ext_vector_type(4))) float f32x4;

#define GLDS(g, l) __builtin_amdgcn_global_load_lds((const __attribute__((address_space(1))) void*)(g), \
                                                    (__attribute__((address_space(3))) void*)(l), 16, 0, 0)

static __device__ __forceinline__ unsigned short f2h(float x) {
    _Float16 h = (_Float16)x;
    return __builtin_bit_cast(unsigned short, h);
}
static __device__ __forceinline__ float h2f(unsigned short u) {
    return (float)__builtin_bit_cast(_Float16, u);
}

// ================= f16 MFMA GEMM, 128x128 tile, BK=64, 4 waves ================
// GM=0: C32[M,CC] = A@Bt + bias  (final linear)
// GM=1: C16[M,256] = f16(A@Bt); fused el/er epilogue (each wave owns one head
//       for its 64 rows -> in-register dot + 16-lane shfl reduce, no atomics)
template<int GM>
__global__ __launch_bounds__(256) void mfma_gemm(const unsigned short* __restrict__ A,
                                                 const unsigned short* __restrict__ Bt,
                                                 const float* __restrict__ bias,
                                                 float* __restrict__ C32,
                                                 unsigned short* __restrict__ C16,
                                                 const float* __restrict__ al,
                                                 const float* __restrict__ ar,
                                                 float* __restrict__ el,
                                                 float* __restrict__ er,
                                                 int M) {
    __shared__ __align__(1024) char lds[32768];   // A tile 16KB | B tile 16KB
    const int tid = threadIdx.x;
    const int lane = tid & 63;
    const int w = tid >> 6;
    const int wr = w >> 1, wc = w & 1;
    const int bm = blockIdx.x * 128;
    const int bn = blockIdx.y * 128;

    f32x4 acc[4][4] = {};

    const int lrow8 = lane >> 3;
    const int cbs = ((lane & 7) << 4) ^ ((lrow8 & 7) << 4);
    const int cbase = w * 8;
    const bool isA = (w < 2);

    const char* gA = (const char*)A;
    const char* gB = (const char*)Bt;

    for (int step = 0; step < 4; ++step) {
        const int k0b = step * 128;              // 64 f16 per K-step
#pragma unroll
        for (int i = 0; i < 8; ++i) {
            int c = cbase + i;
            char* lptr = &lds[c * 1024];
            if (isA) {
                int R = c * 8 + lrow8;
                int grow = bm + R; if (grow >= M) grow = M - 1;
                GLDS(gA + (size_t)grow * 512 + k0b + cbs, lptr);
            } else {
                int nIdx = (c - 16) * 8 + lrow8;
                GLDS(gB + (size_t)(bn + nIdx) * 512 + k0b + cbs, lptr);
            }
        }
        __syncthreads();
#pragma unroll
        for (int kk = 0; kk < 2; ++kk) {
            f16x8 af[4], bfr[4];
            const int o = kk * 64 + ((lane >> 4) << 4);
#pragma unroll
            for (int m = 0; m < 4; ++m) {
                int R = wr * 64 + m * 16 + (lane & 15);
                af[m] = *reinterpret_cast<const f16x8*>(&lds[R * 128 + (o ^ ((R & 7) << 4))]);
            }
#pragma unroll
            for (int n = 0; n < 4; ++n) {
                int Rn = wc * 64 + n * 16 + (lane & 15);
                bfr[n] = *reinterpret_cast<const f16x8*>(&lds[16384 + Rn * 128 + (o ^ ((Rn & 7) << 4))]);
            }
#pragma unroll
            for (int m = 0; m < 4; ++m)
#pragma unroll
                for (int n = 0; n < 4; ++n)
                    acc[m][n] = __builtin_amdgcn_mfma_f32_16x16x32_f16(af[m], bfr[n], acc[m][n], 0, 0, 0);
        }
        __syncthreads();
    }

    const int rb = bm + wr * 64 + ((lane >> 4) << 2);

    if (GM == 0) {
        const int cb2 = bn + wc * 64 + (lane & 15);
#pragma unroll
        for (int m = 0; m < 4; ++m)
#pragma unroll
            for (int n = 0; n < 4; ++n) {
                int col = cb2 + n * 16;
                if (col < CC) {
                    float bb = bias[col];
#pragma unroll
                    for (int j = 0; j < 4; ++j) {
                        int row = rb + m * 16 + j;
                        if (row < M) C32[(size_t)row * CC + col] = acc[m][n][j] + bb;
                    }
                }
            }
    } else {
        // ---- fused el/er: this wave's 64 cols == one full head h ----
        const int h = (bn >> 6) + wc;
        float alv[4], arv[4];
#pragma unroll
        for (int n = 0; n < 4; ++n) {
            alv[n] = al[h * 64 + n * 16 + (lane & 15)];
            arv[n] = ar[h * 64 + n * 16 + (lane & 15)];
        }
#pragma unroll
        for (int m = 0; m < 4; ++m)
#pragma unroll
            for (int j = 0; j < 4; ++j) {
                float pl = acc[m][0][j] * alv[0] + acc[m][1][j] * alv[1]
                         + acc[m][2][j] * alv[2] + acc[m][3][j] * alv[3];
                float pr = acc[m][0][j] * arv[0] + acc[m][1][j] * arv[1]
                         + acc[m][2][j] * arv[2] + acc[m][3][j] * arv[3];
#pragma unroll
                for (int o2 = 1; o2 < 16; o2 <<= 1) {
                    pl += __shfl_xor(pl, o2);
                    pr += __shfl_xor(pr, o2);
                }
                int row = rb + m * 16 + j;
                if ((lane & 15) == 0 && row < M) {
                    el[row * 4 + h] = pl;
                    er[row * 4 + h] = pr;
                }
            }
        // ---- fp16 feat store ----
        const int cb2 = bn + wc * 64 + (lane & 15);
#pragma unroll
        for (int m = 0; m < 4; ++m)
#pragma unroll
            for (int n = 0; n < 4; ++n) {
                int col = cb2 + n * 16;
#pragma unroll
                for (int j = 0; j < 4; ++j) {
                    int row = rb + m * 16 + j;
                    if (row < M) C16[(size_t)row * 256 + col] = f2h(acc[m][n][j]);
                }
            }
    }
}

// ------------- conversions --------------------------------------------------
__global__ __launch_bounds__(256) void f2h4(const float* __restrict__ in,
                                            unsigned short* __restrict__ out, int n4) {
    int i = blockIdx.x * 256 + threadIdx.x;
    if (i >= n4) return;
    float4 v = reinterpret_cast<const float4*>(in)[i];
    ushort4 o;
    o.x = f2h(v.x); o.y = f2h(v.y); o.z = f2h(v.z); o.w = f2h(v.w);
    reinterpret_cast<ushort4*>(out)[i] = o;
}

// Wt[r][n][k] = f16(W[r][k][n])
__global__ __launch_bounds__(256) void wt_kernel(const float* __restrict__ W,
                                                 unsigned short* __restrict__ Wt) {
    int idx = blockIdx.x * 256 + threadIdx.x;
    if (idx >= RR * 65536) return;
    int r = idx >> 16, rem = idx & 65535;
    int n = rem >> 8, k = rem & 255;
    Wt[idx] = f2h(W[(r << 16) + (k << 8) + n]);
}

// Woutt[n][k] = f16(Wout[k][n]) padded to n<256 with zeros
__global__ __launch_bounds__(256) void wout_kernel(const float* __restrict__ Wout,
                                                   unsigned short* __restrict__ Wt) {
    int idx = blockIdx.x * 256 + threadIdx.x;
    if (idx >= 65536) return;
    int n = idx >> 8, k = idx & 255;
    Wt[idx] = (n < CC) ? f2h(Wout[k * CC + n]) : (unsigned short)0;
}

// ================= CSR build (once per call, all 3 relations) ================
__global__ __launch_bounds__(256) void hist_kernel(const int* __restrict__ dst,
                                                   int* __restrict__ deg) {
    int i = blockIdx.x * 256 + threadIdx.x;
    if (i >= RR * EE) return;
    int r = i / EE;
    atomicAdd(&deg[r * NN + dst[i]], 1);
}

__global__ __launch_bounds__(256) void scan_block(const int* __restrict__ deg,
                                                  int* __restrict__ rowptr,
                                                  int* __restrict__ bsum) {
    __shared__ int sh[256];
    int r = blockIdx.y, b = blockIdx.x, t = threadIdx.x;
    int base = b * 1024;
    int v[4];
#pragma unroll
    for (int j = 0; j < 4; ++j) {
        int idx = base + t * 4 + j;
        v[j] = (idx < NN) ? deg[r * NN + idx] : 0;
    }
    int tsum = v[0] + v[1] + v[2] + v[3];
    sh[t] = tsum;
    __syncthreads();
    for (int off = 1; off < 256; off <<= 1) {
        int x = (t >= off) ? sh[t - off] : 0;
        __syncthreads();
        sh[t] += x;
        __syncthreads();
    }
    int run = sh[t] - tsum;
#pragma unroll
    for (int j = 0; j < 4; ++j) {
        int idx = base + t * 4 + j;
        if (idx < NN) rowptr[r * (NN + 1) + idx] = run;
        run += v[j];
    }
    if (t == 255) bsum[r * NB + b] = run;
}

__global__ void scan_bsum(int* __restrict__ bsum, int* __restrict__ rowptr) {
    int r = threadIdx.x;
    if (r >= RR) return;
    int run = 0;
    for (int b = 0; b < NB; ++b) {
        int x = bsum[r * NB + b];
        bsum[r * NB + b] = run;
        run += x;
    }
    rowptr[r * (NN + 1) + NN] = run;
}

__global__ __launch_bounds__(256) void add_off(int* __restrict__ rowptr,
                                               const int* __restrict__ bsum) {
    int r = blockIdx.y, b = blockIdx.x, t = threadIdx.x;
    int o = bsum[r * NB + b];
#pragma unroll
    for (int j = 0; j < 4; ++j) {
        int idx = b * 1024 + t * 4 + j;
        if (idx < NN) rowptr[r * (NN + 1) + idx] += o;
    }
}

__global__ __launch_bounds__(256) void fill_kernel(const int* __restrict__ src,
                                                   const int* __restrict__ dst,
                                                   const int* __restrict__ rowptr,
                                                   int* __restrict__ cursor,
                                                   int* __restrict__ csrc) {
    int i = blockIdx.x * 256 + threadIdx.x;
    if (i >= RR * EE) return;
    int r = i / EE;
    int d = dst[i], s = src[i];
    int pos = rowptr[r * (NN + 1) + d] + atomicAdd(&cursor[r * NN + d], 1);
    csrc[(size_t)r * EE + pos] = s;
}

// ========== merged 3-relation softmax+aggregation: one wave per dst ==========
// Output accumulated entirely in registers: cur = sum_r(b_r) + sum_r(softmax_r).
// RELU=1: layer-0 epilogue (relu); RELU=0: layer-1 (plain). fp16 out.
template<int RELU>
__global__ __launch_bounds__(256) void agg3_kernel(const int* __restrict__ csrc,      // [3][EE]
                                                   const int* __restrict__ rowptr,    // [3][NN+1]
                                                   const float* __restrict__ el,      // [3][NN*4]
                                                   const float* __restrict__ er,      // [3][NN*4]
                                                   const unsigned short* __restrict__ feat, // [3][NN*256]
                                                   const float* __restrict__ brel,    // [3][256]
                                                   unsigned short* __restrict__ hout) {
    int wid = (blockIdx.x * 256 + threadIdx.x) >> 6;
    int lane = threadIdx.x & 63;
    if (wid >= NN) return;
    int d = wid;
    int h = lane >> 4;
    int f0 = lane * 4;

    float4 bA = *reinterpret_cast<const float4*>(brel + f0);
    float4 bB = *reinterpret_cast<const float4*>(brel + 256 + f0);
    float4 bC = *reinterpret_cast<const float4*>(brel + 512 + f0);
    float4 cur = make_float4(bA.x + bB.x + bC.x, bA.y + bB.y + bC.y,
                             bA.z + bB.z + bC.z, bA.w + bB.w + bC.w);

#pragma unroll
    for (int r = 0; r < RR; ++r) {
        int p0 = rowptr[r * (NN + 1) + d], p1 = rowptr[r * (NN + 1) + d + 1];
        if (p0 == p1) continue;
        float erd = er[(size_t)r * NN * 4 + d * 4 + h];
        const float* elr = el + (size_t)r * NN * 4;
        const unsigned short* fr = feat + (size_t)r * NN * 256;
        const int* cs = csrc + (size_t)r * EE;
        float4 a = make_float4(0.f, 0.f, 0.f, 0.f);
        float zs = 0.f;
        for (int p = p0; p < p1; ++p) {
            int s = cs[p];
            float v = elr[s * 4 + h] + erd;
            v = v > 0.f ? v : 0.2f * v;
            float wgt = __expf(v);
            zs += wgt;
            ushort4 f = *reinterpret_cast<const ushort4*>(fr + (size_t)s * 256 + f0);
            a.x += wgt * h2f(f.x); a.y += wgt * h2f(f.y);
            a.z += wgt * h2f(f.z); a.w += wgt * h2f(f.w);
        }
        float inv = 1.f / zs;
        cur.x += a.x * inv; cur.y += a.y * inv;
        cur.z += a.z * inv; cur.w += a.w * inv;
    }
    if (RELU) {
        cur.x = fmaxf(cur.x, 0.f); cur.y = fmaxf(cur.y, 0.f);
        cur.z = fmaxf(cur.z, 0.f); cur.w = fmaxf(cur.w, 0.f);
    }
    ushort4 o;
    o.x = f2h(cur.x); o.y = f2h(cur.y); o.z = f2h(cur.z); o.w = f2h(cur.w);
    *reinterpret_cast<ushort4*>(hout + (size_t)d * 256 + f0) = o;
}

extern "C" void kernel_launch(void* const* d_in, const int* in_sizes, int n_in,
                              void* d_out, int out_size, void* d_ws, size_t ws_size,
                              hipStream_t stream) {
    const float* x    = (const float*)d_in[0];
    const int*   src  = (const int*)d_in[1];
    const int*   dst  = (const int*)d_in[2];
    const float* W1   = (const float*)d_in[3];
    const float* al1  = (const float*)d_in[4];
    const float* ar1  = (const float*)d_in[5];
    const float* b1   = (const float*)d_in[6];
    const float* W2   = (const float*)d_in[7];
    const float* al2  = (const float*)d_in[8];
    const float* ar2  = (const float*)d_in[9];
    const float* b2   = (const float*)d_in[10];
    const float* Wout = (const float*)d_in[11];
    const float* bout = (const float*)d_in[12];
    float* out = (float*)d_out;

    // ---- workspace layout: every sub-buffer 256B-aligned ----
    char* base = (char*)d_ws;
    size_t off = 0;
    auto alloc = [&](size_t bytes) -> char* {
        char* p = base + off;
        off = (off + bytes + 255) & ~(size_t)255;
        return p;
    };
    size_t NF = (size_t)NN * HFF;                 // 25.6M elements
    unsigned short* feath = (unsigned short*)alloc(RR * NF * 2);  // fp16 feat, 3 relations
    float* el   = (float*)alloc((size_t)RR * NN * NH * 4);
    float* er   = (float*)alloc((size_t)RR * NN * NH * 4);
    int* deg    = (int*)alloc((size_t)RR * NN * 4 * 2);       // deg + cursor contiguous
    int* cursor = deg + (size_t)RR * NN;
    int* rowptr = (int*)alloc((size_t)RR * (NN + 1) * 4);
    int* bsum   = (int*)alloc((size_t)RR * NB * 4);
    int* csrc   = (int*)alloc((size_t)RR * EE * 4);
    unsigned short* xh    = (unsigned short*)alloc(NF * 2);   // x_f16 / h1_f16 / h2_f16
    unsigned short* wth   = (unsigned short*)alloc((size_t)2 * RR * 65536 * 2);
    unsigned short* wouth = (unsigned short*)alloc((size_t)65536 * 2);

    int n4Blocks = (int)((NF / 4 + 255) / 256);
    int reBlocks = (RR * EE + 255) / 256;
    int aggBlocks = (NN * 64 + 255) / 256;
    dim3 ggrid((NN + 127) / 128, 2);

    // ---- CSR build (shared by both layers) ----
    hipMemsetAsync(deg, 0, (size_t)RR * NN * sizeof(int) * 2, stream);
    hist_kernel<<<reBlocks, 256, 0, stream>>>(dst, deg);
    scan_block<<<dim3(NB, RR), 256, 0, stream>>>(deg, rowptr, bsum);
    scan_bsum<<<1, 64, 0, stream>>>(bsum, rowptr);
    add_off<<<dim3(NB, RR), 256, 0, stream>>>(rowptr, bsum);
    fill_kernel<<<reBlocks, 256, 0, stream>>>(src, dst, rowptr, cursor, csrc);

    // ---- input conversion + all weight transposes up front ----
    f2h4<<<n4Blocks, 256, 0, stream>>>(x, xh, (int)(NF / 4));
    wt_kernel<<<(RR * 65536) / 256, 256, 0, stream>>>(W1, wth);
    wt_kernel<<<(RR * 65536) / 256, 256, 0, stream>>>(W2, wth + (size_t)RR * 65536);
    wout_kernel<<<65536 / 256, 256, 0, stream>>>(Wout, wouth);

    for (int layer = 0; layer < 2; ++layer) {
        const float* al = layer ? al2 : al1;
        const float* ar = layer ? ar2 : ar1;
        const float* b  = layer ? b2 : b1;
        const unsigned short* wl = wth + (size_t)layer * RR * 65536;

        for (int r = 0; r < RR; ++r)
            mfma_gemm<1><<<ggrid, 256, 0, stream>>>(xh, wl + (size_t)r * 65536, nullptr,
                                                    nullptr, feath + (size_t)r * NF,
                                                    al + r * NH * DD, ar + r * NH * DD,
                                                    el + (size_t)r * NN * NH,
                                                    er + (size_t)r * NN * NH, NN);
        if (layer == 0)
            agg3_kernel<1><<<aggBlocks, 256, 0, stream>>>(csrc, rowptr, el, er, feath, b, xh);
        else
            agg3_kernel<0><<<aggBlocks, 256, 0, stream>>>(csrc, rowptr, el, er, feath, b, xh);
    }

    // ---- output linear (+ bout) ----
    mfma_gemm<0><<<ggrid, 256, 0, stream>>>(xh, wouth, bout, out, nullptr,
                                            nullptr, nullptr, nullptr, nullptr, NN);
}